// Round 2
// baseline (195.944 us; speedup 1.0000x reference)
//
#include <hip/hip_runtime.h>
#include <hip/hip_bf16.h>

// Problem: B=2, N=4096, QD=512, HEADS=8, DIM_HEAD=64, INNER=512
// softmax scale 1/8 AND log2(e) folded into Q: P = exp2(S').
//
// R15: R14 with the permlane32_swap direction fixed.
// swap(dst,src): new_dst={dst_lo,src_lo}, new_src={dst_hi,src_hi};
// PV A-frag needs u[0]={a0_lo,b0_lo}, u[2]={a0_hi,b0_hi} -> swap(a0,b0).
// R14 had swap(b0,a0) which delivered key-scrambled P (absmax 1.1e-2).
// prep / qkv_fused / out_proj unchanged from R13 (192.7 us session best).

typedef __attribute__((ext_vector_type(8))) short short8;
typedef __attribute__((ext_vector_type(4))) float floatx4;
typedef __attribute__((ext_vector_type(16))) float floatx16;

#define MFMA16(a, b, c) __builtin_amdgcn_mfma_f32_16x16x32_bf16((a), (b), (c), 0, 0, 0)
#define MFMA32(a, b, c) __builtin_amdgcn_mfma_f32_32x32x16_bf16((a), (b), (c), 0, 0, 0)

#if __has_builtin(__builtin_amdgcn_exp2f)
#define EXP2(x) __builtin_amdgcn_exp2f(x)
#else
#define EXP2(x) exp2f(x)
#endif

// (1/8) * log2(e)
#define QSCALE 0.18033688011112042f

// fp32 -> bf16 (round-to-nearest-even)
static __device__ __forceinline__ unsigned short f2b(float f) {
  unsigned int u = __float_as_uint(f);
  u += 0x7FFFu + ((u >> 16) & 1u);
  return (unsigned short)(u >> 16);
}

// packed pair fp32 -> 2x bf16 in one u32
static __device__ __forceinline__ unsigned int pkb(float a, float b) {
  float2 t{a, b};
  __hip_bfloat162 h = __float22bfloat162_rn(t);
  union { __hip_bfloat162 h2; unsigned int u; } cv;
  cv.h2 = h;
  return cv.u;
}

// async global->LDS DMA: 16 B/lane; dest = wave-uniform base + lane*16.
static __device__ __forceinline__ void dma16(const unsigned short* g,
                                             unsigned short* l) {
  __builtin_amdgcn_global_load_lds(
      (const __attribute__((address_space(1))) unsigned int*)g,
      (__attribute__((address_space(3))) unsigned int*)l, 16, 0, 0);
}

// ---------------------------------------------------------------------------
// Kernel 0: prep — z 0..3: W transpose+bf16; z 4..11: x->bf16 slabs.
// ---------------------------------------------------------------------------
__global__ __launch_bounds__(256) void prep_kernel(
    const float* __restrict__ Wq, const float* __restrict__ Wk,
    const float* __restrict__ Wv, const float* __restrict__ Wo,
    const float* __restrict__ x, unsigned short* __restrict__ wtq,
    unsigned short* __restrict__ wtk, unsigned short* __restrict__ wtv,
    unsigned short* __restrict__ wto, unsigned short* __restrict__ xb) {
  const int z = blockIdx.z;
  const int tid = threadIdx.x;
  if (z >= 4) {
    const int bid = (z - 4) * 256 + blockIdx.y * 16 + blockIdx.x;
    const int idx = (bid * 256 + tid) * 8;
    const float4 a = *(const float4*)(x + idx);
    const float4 b = *(const float4*)(x + idx + 4);
    unsigned int u[4] = {pkb(a.x, a.y), pkb(a.z, a.w), pkb(b.x, b.y),
                         pkb(b.z, b.w)};
    *(short8*)(xb + idx) = *(short8*)u;
    return;
  }
  const float* __restrict__ W = (z == 0) ? Wq : (z == 1) ? Wk : (z == 2) ? Wv : Wo;
  unsigned short* __restrict__ T = (z == 0) ? wtq : (z == 1) ? wtk : (z == 2) ? wtv : wto;
  const int k0 = blockIdx.x * 32, c0 = blockIdx.y * 32;
  __shared__ float Ts[32][33];
  const int r = tid >> 3, cc = (tid & 7) * 4;
  const float4 v = *(const float4*)(W + (k0 + r) * 512 + c0 + cc);
  Ts[r][cc] = v.x; Ts[r][cc + 1] = v.y; Ts[r][cc + 2] = v.z; Ts[r][cc + 3] = v.w;
  __syncthreads();
  const unsigned long long uu =
      (unsigned long long)pkb(Ts[cc][r], Ts[cc + 1][r]) |
      ((unsigned long long)pkb(Ts[cc + 2][r], Ts[cc + 3][r]) << 32);
  *(unsigned long long*)(T + (c0 + r) * 512 + k0 + cc) = uu;
}

// ---------------------------------------------------------------------------
// Kernel 1: fused QKV — all-DMA double-buffered single-barrier pipeline.
// M=128 x N=32 per z, BK=64 (8 ksteps).  Dense 128B rows, XOR chunk swizzle.
// ---------------------------------------------------------------------------
__global__ __launch_bounds__(256) void qkv_fused_kernel(
    const unsigned short* __restrict__ xb, const unsigned short* __restrict__ wtq,
    const unsigned short* __restrict__ wtk,
    const unsigned short* __restrict__ wtv, unsigned short* __restrict__ qo,
    unsigned short* __restrict__ ko, unsigned short* __restrict__ vo) {
  const int m0 = blockIdx.x * 128;  // 64
  const int c0 = blockIdx.y * 32;   // 16
  __shared__ __align__(16) unsigned short As[2][128 * 64];    // 32 KB
  __shared__ __align__(16) unsigned short Bs[2][3][32 * 64];  // 24 KB
  const int tid = threadIdx.x;
  const int lane = tid & 63, w = tid >> 6;
  const int i = lane & 15, q = lane >> 4;
  const int sl = i & 7;
  const int dr = lane >> 3, dc = lane & 7;
  const int sch = (dc ^ dr) * 8;
  const unsigned short* ag = xb + (m0 + w * 32 + dr) * 512 + sch;
  const unsigned short* bg[3];
  bg[0] = wtq + (c0 + w * 8 + dr) * 512 + sch;
  bg[1] = wtk + (c0 + w * 8 + dr) * 512 + sch;
  bg[2] = wtv + (c0 + w * 8 + dr) * 512 + sch;

  floatx4 acc[3][2][2] = {};

#pragma unroll
  for (int p = 0; p < 4; ++p) dma16(ag + p * 8 * 512, &As[0][(w * 32 + p * 8) * 64]);
#pragma unroll
  for (int z = 0; z < 3; ++z) dma16(bg[z], &Bs[0][z][(w * 8) * 64]);
  __syncthreads();

  int buf = 0;
  for (int ks = 0; ks < 8; ++ks) {
    if (ks < 7) {
      const int k1 = (ks + 1) * 64;
#pragma unroll
      for (int p = 0; p < 4; ++p)
        dma16(ag + p * 8 * 512 + k1, &As[buf ^ 1][(w * 32 + p * 8) * 64]);
#pragma unroll
      for (int z = 0; z < 3; ++z)
        dma16(bg[z] + k1, &Bs[buf ^ 1][z][(w * 8) * 64]);
    }
#pragma unroll
    for (int kc = 0; kc < 2; ++kc) {
      short8 af[2];
#pragma unroll
      for (int t = 0; t < 2; ++t)
        af[t] = *(const short8*)&As[buf][(w * 32 + t * 16 + i) * 64 +
                                        (((kc * 4 + q) ^ sl) * 8)];
#pragma unroll
      for (int z = 0; z < 3; ++z)
#pragma unroll
        for (int g = 0; g < 2; ++g) {
          const short8 bf = *(const short8*)&Bs[buf][z][(g * 16 + i) * 64 +
                                                        (((kc * 4 + q) ^ sl) * 8)];
#pragma unroll
          for (int t = 0; t < 2; ++t)
            acc[z][t][g] = MFMA16(af[t], bf, acc[z][t][g]);
        }
    }
    __syncthreads();
    buf ^= 1;
  }
#pragma unroll
  for (int z = 0; z < 3; ++z)
#pragma unroll
    for (int t = 0; t < 2; ++t)
#pragma unroll
      for (int g = 0; g < 2; ++g) {
        const int col = c0 + g * 16 + i;
        const int h = col >> 6, d = col & 63;
        const int row0 = m0 + w * 32 + t * 16 + q * 4;
        const int b = row0 >> 12;
        const int n0 = row0 & 4095;
        if (z == 2) {
          unsigned int* dst =
              (unsigned int*)&vo[(((b * 8 + h) * 64 + d) << 12) + n0];
          dst[0] = pkb(acc[z][t][g][0], acc[z][t][g][1]);
          dst[1] = pkb(acc[z][t][g][2], acc[z][t][g][3]);
        } else {
          unsigned short* dst = (z == 0) ? qo : ko;
          const float sc = (z == 0) ? QSCALE : 1.0f;
#pragma unroll
          for (int r = 0; r < 4; ++r)
            dst[(((b * 8 + h) << 12) + (n0 + r)) * 64 + d] =
                f2b(acc[z][t][g][r] * sc);
        }
      }
}

// ---------------------------------------------------------------------------
// Kernel 2: flash attention — 32x32x16 MFMA, in-register P.
// 512 threads = 8 waves = 4 row-tiles x 2 key groups; bh in low grid bits;
// single-buffered K/V with register prefetch; XOR-swizzled LDS.
// Swapped QK (A=K, B=Q): lane holds P[32 keys] for query (lane&31);
// PV A-frags built in-register via v_cvt_pk_bf16_f32 + v_permlane32_swap_b32.
// Row-sum L accumulated as per-lane f32 (no ones-MFMA), combined in epilogue.
// ---------------------------------------------------------------------------
__global__ __launch_bounds__(512, 4) void flash_kernel(
    const unsigned short* __restrict__ Q, const unsigned short* __restrict__ K,
    const unsigned short* __restrict__ Vt, unsigned short* __restrict__ O) {
  const int bh = blockIdx.x;        // 16
  const int m0 = blockIdx.y * 128;  // 32
  const int tid = threadIdx.x;
  const int lane = tid & 63, w = tid >> 6;
  const int ql = lane & 31, hi = lane >> 5;
  const int rt = w & 3;   // row tile (32 rows)
  const int kg = w >> 2;  // key group (2048 keys)
  const unsigned short* qp = Q + bh * (4096 * 64);
  const unsigned short* kp = K + bh * (4096 * 64);
  const unsigned short* vp = Vt + bh * (64 * 4096);

  __shared__ __align__(16) unsigned short SM[20480];  // 40 KB
  unsigned short* Ks = SM + kg * 4096;         // [64 keys][64 d], swizzled
  unsigned short* Vs = SM + 8192 + kg * 4096;  // [64 d][64 keys], swizzled

  const int srow = (tid & 255) >> 3;  // 0..31 (and +32)
  const int c0s = tid & 7;            // source 16B chunk
  const int sw8 = (c0s ^ (srow & 7)) * 8;
  const unsigned short* kgp = kp + (kg * 2048 + srow) * 64 + c0s * 8;
  const unsigned short* vgp = vp + srow * 4096 + kg * 2048 + c0s * 8;

  // Q fragments (B operand of swapped QK, 32x32x16): lane: col=ql, k=hi*8+j.
  short8 qf[4];
  {
    const unsigned short* qrp = qp + (m0 + rt * 32 + ql) * 64 + hi * 8;
#pragma unroll
    for (int ks = 0; ks < 4; ++ks) qf[ks] = *(const short8*)(qrp + ks * 16);
  }

  floatx16 accO[2] = {};
  float accLp = 0.f;
  const int sx = ql & 7;

  *(short8*)&Ks[srow * 64 + sw8] = *(const short8*)(kgp);
  *(short8*)&Ks[(srow + 32) * 64 + sw8] = *(const short8*)(kgp + 32 * 64);
  *(short8*)&Vs[srow * 64 + sw8] = *(const short8*)(vgp);
  *(short8*)&Vs[(srow + 32) * 64 + sw8] = *(const short8*)(vgp + 32 * 4096);
  __syncthreads();

  for (int jt = 0; jt < 32; ++jt) {
    short8 kn0, kn1, vn0, vn1;
    if (jt < 31) {
      kn0 = *(const short8*)(kgp + (jt + 1) * 4096);
      kn1 = *(const short8*)(kgp + (jt + 1) * 4096 + 32 * 64);
      vn0 = *(const short8*)(vgp + (jt + 1) * 64);
      vn1 = *(const short8*)(vgp + (jt + 1) * 64 + 32 * 4096);
    }

    short8 pa[4];  // PV A-frags: keys 16*idx .. 16*idx+15
#pragma unroll
    for (int kt = 0; kt < 2; ++kt) {
      floatx16 c;
#pragma unroll
      for (int j = 0; j < 16; ++j) c[j] = 0.0f;
#pragma unroll
      for (int ks = 0; ks < 4; ++ks) {
        const short8 kf = *(const short8*)&Ks[(kt * 32 + ql) * 64 +
                                             (((2 * ks + hi) ^ sx) * 8)];
        c = MFMA32(kf, qf[ks], c);
      }
      // P = exp2(S); lane holds keys (r&3)+8*(r>>2)+4*hi (+32*kt), query ql.
      float e[16];
#pragma unroll
      for (int j = 0; j < 16; ++j) e[j] = EXP2(c[j]);
      accLp += (((e[0] + e[1]) + (e[2] + e[3])) +
                ((e[4] + e[5]) + (e[6] + e[7]))) +
               (((e[8] + e[9]) + (e[10] + e[11])) +
                ((e[12] + e[13]) + (e[14] + e[15])));
      // Build A-frags for PV (A row=query=ql, k=key hi*8+j per 16-key step):
      //   u[0]={a0_lo,b0_lo}  u[1]={c1_lo,d1_lo}
      //   u[2]={a0_hi,b0_hi}  u[3]={c1_hi,d1_hi}
      // swap(dst,src): new_dst={dst_lo,src_lo}, new_src={dst_hi,src_hi}.
#pragma unroll
      for (int s2 = 0; s2 < 2; ++s2) {
        unsigned int a0 = pkb(e[8 * s2 + 0], e[8 * s2 + 1]);
        unsigned int c1 = pkb(e[8 * s2 + 2], e[8 * s2 + 3]);
        unsigned int b0 = pkb(e[8 * s2 + 4], e[8 * s2 + 5]);
        unsigned int d1 = pkb(e[8 * s2 + 6], e[8 * s2 + 7]);
        asm("v_permlane32_swap_b32 %0, %1" : "+v"(a0), "+v"(b0));
        asm("v_permlane32_swap_b32 %0, %1" : "+v"(c1), "+v"(d1));
        union { unsigned int u[4]; short8 s; } cv;
        cv.u[0] = a0; cv.u[1] = c1; cv.u[2] = b0; cv.u[3] = d1;
        pa[kt * 2 + s2] = cv.s;
      }
    }
    // PV: D[q][d] += P[q][k] * V[k][d];  B-frag from Vs[d][k].
#pragma unroll
    for (int dt = 0; dt < 2; ++dt)
#pragma unroll
      for (int ks2 = 0; ks2 < 4; ++ks2) {
        const short8 vf = *(const short8*)&Vs[(dt * 32 + ql) * 64 +
                                              (((2 * ks2 + hi) ^ sx) * 8)];
        accO[dt] = MFMA32(pa[ks2], vf, accO[dt]);
      }
    __syncthreads();
    if (jt < 31) {
      *(short8*)&Ks[srow * 64 + sw8] = kn0;
      *(short8*)&Ks[(srow + 32) * 64 + sw8] = kn1;
      *(short8*)&Vs[srow * 64 + sw8] = vn0;
      *(short8*)&Vs[(srow + 32) * 64 + sw8] = vn1;
    }
    __syncthreads();
  }

  // kg reduction: kg=1 dumps accO (32 f32) + accLp; kg=0 adds.
  float* MB = (float*)SM;
  if (kg == 1) {
    float* dst = MB + (rt * 64 + lane) * 40;
#pragma unroll
    for (int dt = 0; dt < 2; ++dt)
#pragma unroll
      for (int r = 0; r < 16; ++r) dst[dt * 16 + r] = accO[dt][r];
    dst[32] = accLp;
  }
  __syncthreads();
  if (kg == 1) return;
  {
    const float* src = MB + (rt * 64 + lane) * 40;
#pragma unroll
    for (int dt = 0; dt < 2; ++dt)
#pragma unroll
      for (int r = 0; r < 16; ++r) accO[dt][r] += src[dt * 16 + r];
    accLp += src[32];
  }

  const float Lfull = accLp + __shfl(accLp, lane ^ 32, 64);
  const float invL = 1.0f / Lfull;
  const int b = bh >> 3, h = bh & 7;
#pragma unroll
  for (int r = 0; r < 16; ++r) {
    const int qrow = (r & 3) + 8 * (r >> 2) + 4 * hi;
    const float iv = __shfl(invL, qrow, 64);
    const int n = m0 + rt * 32 + qrow;
#pragma unroll
    for (int dt = 0; dt < 2; ++dt) {
      const int col = h * 64 + dt * 32 + ql;
      O[((b << 12) + n) * 512 + col] = f2b(accO[dt][r] * iv);
    }
  }
}

// ---------------------------------------------------------------------------
// Kernel 3: out projection — all-DMA dbuf single-barrier, 64x64, BK=64.
// ---------------------------------------------------------------------------
__global__ __launch_bounds__(256) void out_proj_kernel(
    const unsigned short* __restrict__ A, const unsigned short* __restrict__ wto,
    const float* __restrict__ bo, float* __restrict__ out) {
  const int m0 = blockIdx.x * 64, c0 = blockIdx.y * 64;
  __shared__ __align__(16) unsigned short As[2][64 * 64];  // 16 KB
  __shared__ __align__(16) unsigned short Bs[2][64 * 64];  // 16 KB
  const int tid = threadIdx.x;
  const int lane = tid & 63, w = tid >> 6;
  const int i = lane & 15, q = lane >> 4;
  const int wy = w >> 1, wx = w & 1;
  const int sl = i & 7;
  const int dr = lane >> 3, dc = lane & 7;
  const int sch = (dc ^ dr) * 8;
  const unsigned short* ag = A + (m0 + w * 16 + dr) * 512 + sch;
  const unsigned short* bg = wto + (c0 + w * 16 + dr) * 512 + sch;

  floatx4 acc[2][2] = {};
#pragma unroll
  for (int p = 0; p < 2; ++p) {
    dma16(ag + p * 8 * 512, &As[0][(w * 16 + p * 8) * 64]);
    dma16(bg + p * 8 * 512, &Bs[0][(w * 16 + p * 8) * 64]);
  }
  __syncthreads();

  int buf = 0;
  for (int ks = 0; ks < 8; ++ks) {
    if (ks < 7) {
      const int k1 = (ks + 1) * 64;
#pragma unroll
      for (int p = 0; p < 2; ++p) {
        dma16(ag + p * 8 * 512 + k1, &As[buf ^ 1][(w * 16 + p * 8) * 64]);
        dma16(bg + p * 8 * 512 + k1, &Bs[buf ^ 1][(w * 16 + p * 8) * 64]);
      }
    }
#pragma unroll
    for (int kc = 0; kc < 2; ++kc) {
      short8 af[2], bfr[2];
#pragma unroll
      for (int t = 0; t < 2; ++t)
        af[t] = *(const short8*)&As[buf][(wy * 32 + t * 16 + i) * 64 +
                                        (((kc * 4 + q) ^ sl) * 8)];
#pragma unroll
      for (int g = 0; g < 2; ++g)
        bfr[g] = *(const short8*)&Bs[buf][(wx * 32 + g * 16 + i) * 64 +
                                          (((kc * 4 + q) ^ sl) * 8)];
#pragma unroll
      for (int t = 0; t < 2; ++t)
#pragma unroll
        for (int g = 0; g < 2; ++g) acc[t][g] = MFMA16(af[t], bfr[g], acc[t][g]);
    }
    __syncthreads();
    buf ^= 1;
  }
#pragma unroll
  for (int t = 0; t < 2; ++t)
#pragma unroll
    for (int g = 0; g < 2; ++g) {
      const int col = c0 + wx * 32 + g * 16 + i;
      const float bias = bo[col];
#pragma unroll
      for (int r = 0; r < 4; ++r) {
        const int row = m0 + wy * 32 + t * 16 + q * 4 + r;
        out[row * 512 + col] = acc[t][g][r] + bias;
      }
    }
}

// ---------------------------------------------------------------------------
extern "C" void kernel_launch(void* const* d_in, const int* in_sizes, int n_in,
                              void* d_out, int out_size, void* d_ws,
                              size_t ws_size, hipStream_t stream) {
  const float* x = (const float*)d_in[0];
  const float* Wq = (const float*)d_in[1];
  const float* Wk = (const float*)d_in[2];
  const float* Wv = (const float*)d_in[3];
  const float* Wo = (const float*)d_in[4];
  const float* bo = (const float*)d_in[5];
  float* out = (float*)d_out;

  const size_t tsz = (size_t)16 * 4096 * 64;  // B*N*INNER elems
  unsigned short* qws = (unsigned short*)d_ws;
  unsigned short* kws = qws + tsz;
  unsigned short* vws = kws + tsz;
  unsigned short* ows = vws + tsz;
  unsigned short* wtq = ows + tsz;
  unsigned short* wtk = wtq + 512 * 512;
  unsigned short* wtv = wtk + 512 * 512;
  unsigned short* wto = wtv + 512 * 512;
  unsigned short* xb = wto + 512 * 512;  // x as bf16, [8192,512]

  prep_kernel<<<dim3(16, 16, 12), 256, 0, stream>>>(Wq, Wk, Wv, Wo, x, wtq,
                                                    wtk, wtv, wto, xb);
  qkv_fused_kernel<<<dim3(64, 16), 256, 0, stream>>>(xb, wtq, wtk, wtv, qws,
                                                     kws, vws);
  flash_kernel<<<dim3(16, 32), 512, 0, stream>>>(qws, kws, vws, ows);
  out_proj_kernel<<<dim3(128, 8), 256, 0, stream>>>(ows, wto, bo, out);
}

// Round 4
// 192.604 us; speedup vs baseline: 1.0173x; 1.0173x over previous
//
#include <hip/hip_runtime.h>
#include <hip/hip_bf16.h>

// Problem: B=2, N=4096, QD=512, HEADS=8, DIM_HEAD=64, INNER=512
// softmax scale 1/8 AND log2(e) folded into Q: P = exp2(S').
//
// R17 = R16 resubmitted verbatim (R16 bench was an infra failure, no data).
// flash = R15 (32x32x16 MFMA, in-register P via permlane32_swap)
//  + K/V LDS double-buffer -> ONE barrier per jt (was 2)
//  + s_setprio(1) around QK and PV MFMA clusters (T5, m191 attn +4-7%).
// LDS 40->64 KB (2 blocks/CU x 64 = 128 <= 160 KB, occupancy unchanged).
// prep / qkv_fused / out_proj unchanged from R13.

typedef __attribute__((ext_vector_type(8))) short short8;
typedef __attribute__((ext_vector_type(4))) float floatx4;
typedef __attribute__((ext_vector_type(16))) float floatx16;

#define MFMA16(a, b, c) __builtin_amdgcn_mfma_f32_16x16x32_bf16((a), (b), (c), 0, 0, 0)
#define MFMA32(a, b, c) __builtin_amdgcn_mfma_f32_32x32x16_bf16((a), (b), (c), 0, 0, 0)

#if __has_builtin(__builtin_amdgcn_exp2f)
#define EXP2(x) __builtin_amdgcn_exp2f(x)
#else
#define EXP2(x) exp2f(x)
#endif

// (1/8) * log2(e)
#define QSCALE 0.18033688011112042f

// fp32 -> bf16 (round-to-nearest-even)
static __device__ __forceinline__ unsigned short f2b(float f) {
  unsigned int u = __float_as_uint(f);
  u += 0x7FFFu + ((u >> 16) & 1u);
  return (unsigned short)(u >> 16);
}

// packed pair fp32 -> 2x bf16 in one u32
static __device__ __forceinline__ unsigned int pkb(float a, float b) {
  float2 t{a, b};
  __hip_bfloat162 h = __float22bfloat162_rn(t);
  union { __hip_bfloat162 h2; unsigned int u; } cv;
  cv.h2 = h;
  return cv.u;
}

// async global->LDS DMA: 16 B/lane; dest = wave-uniform base + lane*16.
static __device__ __forceinline__ void dma16(const unsigned short* g,
                                             unsigned short* l) {
  __builtin_amdgcn_global_load_lds(
      (const __attribute__((address_space(1))) unsigned int*)g,
      (__attribute__((address_space(3))) unsigned int*)l, 16, 0, 0);
}

// ---------------------------------------------------------------------------
// Kernel 0: prep — z 0..3: W transpose+bf16; z 4..11: x->bf16 slabs.
// ---------------------------------------------------------------------------
__global__ __launch_bounds__(256) void prep_kernel(
    const float* __restrict__ Wq, const float* __restrict__ Wk,
    const float* __restrict__ Wv, const float* __restrict__ Wo,
    const float* __restrict__ x, unsigned short* __restrict__ wtq,
    unsigned short* __restrict__ wtk, unsigned short* __restrict__ wtv,
    unsigned short* __restrict__ wto, unsigned short* __restrict__ xb) {
  const int z = blockIdx.z;
  const int tid = threadIdx.x;
  if (z >= 4) {
    const int bid = (z - 4) * 256 + blockIdx.y * 16 + blockIdx.x;
    const int idx = (bid * 256 + tid) * 8;
    const float4 a = *(const float4*)(x + idx);
    const float4 b = *(const float4*)(x + idx + 4);
    unsigned int u[4] = {pkb(a.x, a.y), pkb(a.z, a.w), pkb(b.x, b.y),
                         pkb(b.z, b.w)};
    *(short8*)(xb + idx) = *(short8*)u;
    return;
  }
  const float* __restrict__ W = (z == 0) ? Wq : (z == 1) ? Wk : (z == 2) ? Wv : Wo;
  unsigned short* __restrict__ T = (z == 0) ? wtq : (z == 1) ? wtk : (z == 2) ? wtv : wto;
  const int k0 = blockIdx.x * 32, c0 = blockIdx.y * 32;
  __shared__ float Ts[32][33];
  const int r = tid >> 3, cc = (tid & 7) * 4;
  const float4 v = *(const float4*)(W + (k0 + r) * 512 + c0 + cc);
  Ts[r][cc] = v.x; Ts[r][cc + 1] = v.y; Ts[r][cc + 2] = v.z; Ts[r][cc + 3] = v.w;
  __syncthreads();
  const unsigned long long uu =
      (unsigned long long)pkb(Ts[cc][r], Ts[cc + 1][r]) |
      ((unsigned long long)pkb(Ts[cc + 2][r], Ts[cc + 3][r]) << 32);
  *(unsigned long long*)(T + (c0 + r) * 512 + k0 + cc) = uu;
}

// ---------------------------------------------------------------------------
// Kernel 1: fused QKV — all-DMA double-buffered single-barrier pipeline.
// M=128 x N=32 per z, BK=64 (8 ksteps).  Dense 128B rows, XOR chunk swizzle.
// ---------------------------------------------------------------------------
__global__ __launch_bounds__(256) void qkv_fused_kernel(
    const unsigned short* __restrict__ xb, const unsigned short* __restrict__ wtq,
    const unsigned short* __restrict__ wtk,
    const unsigned short* __restrict__ wtv, unsigned short* __restrict__ qo,
    unsigned short* __restrict__ ko, unsigned short* __restrict__ vo) {
  const int m0 = blockIdx.x * 128;  // 64
  const int c0 = blockIdx.y * 32;   // 16
  __shared__ __align__(16) unsigned short As[2][128 * 64];    // 32 KB
  __shared__ __align__(16) unsigned short Bs[2][3][32 * 64];  // 24 KB
  const int tid = threadIdx.x;
  const int lane = tid & 63, w = tid >> 6;
  const int i = lane & 15, q = lane >> 4;
  const int sl = i & 7;
  const int dr = lane >> 3, dc = lane & 7;
  const int sch = (dc ^ dr) * 8;
  const unsigned short* ag = xb + (m0 + w * 32 + dr) * 512 + sch;
  const unsigned short* bg[3];
  bg[0] = wtq + (c0 + w * 8 + dr) * 512 + sch;
  bg[1] = wtk + (c0 + w * 8 + dr) * 512 + sch;
  bg[2] = wtv + (c0 + w * 8 + dr) * 512 + sch;

  floatx4 acc[3][2][2] = {};

#pragma unroll
  for (int p = 0; p < 4; ++p) dma16(ag + p * 8 * 512, &As[0][(w * 32 + p * 8) * 64]);
#pragma unroll
  for (int z = 0; z < 3; ++z) dma16(bg[z], &Bs[0][z][(w * 8) * 64]);
  __syncthreads();

  int buf = 0;
  for (int ks = 0; ks < 8; ++ks) {
    if (ks < 7) {
      const int k1 = (ks + 1) * 64;
#pragma unroll
      for (int p = 0; p < 4; ++p)
        dma16(ag + p * 8 * 512 + k1, &As[buf ^ 1][(w * 32 + p * 8) * 64]);
#pragma unroll
      for (int z = 0; z < 3; ++z)
        dma16(bg[z] + k1, &Bs[buf ^ 1][z][(w * 8) * 64]);
    }
#pragma unroll
    for (int kc = 0; kc < 2; ++kc) {
      short8 af[2];
#pragma unroll
      for (int t = 0; t < 2; ++t)
        af[t] = *(const short8*)&As[buf][(w * 32 + t * 16 + i) * 64 +
                                        (((kc * 4 + q) ^ sl) * 8)];
#pragma unroll
      for (int z = 0; z < 3; ++z)
#pragma unroll
        for (int g = 0; g < 2; ++g) {
          const short8 bf = *(const short8*)&Bs[buf][z][(g * 16 + i) * 64 +
                                                        (((kc * 4 + q) ^ sl) * 8)];
#pragma unroll
          for (int t = 0; t < 2; ++t)
            acc[z][t][g] = MFMA16(af[t], bf, acc[z][t][g]);
        }
    }
    __syncthreads();
    buf ^= 1;
  }
#pragma unroll
  for (int z = 0; z < 3; ++z)
#pragma unroll
    for (int t = 0; t < 2; ++t)
#pragma unroll
      for (int g = 0; g < 2; ++g) {
        const int col = c0 + g * 16 + i;
        const int h = col >> 6, d = col & 63;
        const int row0 = m0 + w * 32 + t * 16 + q * 4;
        const int b = row0 >> 12;
        const int n0 = row0 & 4095;
        if (z == 2) {
          unsigned int* dst =
              (unsigned int*)&vo[(((b * 8 + h) * 64 + d) << 12) + n0];
          dst[0] = pkb(acc[z][t][g][0], acc[z][t][g][1]);
          dst[1] = pkb(acc[z][t][g][2], acc[z][t][g][3]);
        } else {
          unsigned short* dst = (z == 0) ? qo : ko;
          const float sc = (z == 0) ? QSCALE : 1.0f;
#pragma unroll
          for (int r = 0; r < 4; ++r)
            dst[(((b * 8 + h) << 12) + (n0 + r)) * 64 + d] =
                f2b(acc[z][t][g][r] * sc);
        }
      }
}

// ---------------------------------------------------------------------------
// Kernel 2: flash attention — 32x32x16 MFMA, in-register P, K/V LDS dbuf.
// 512 threads = 8 waves = 4 row-tiles x 2 key groups; bh in low grid bits;
// ONE barrier per jt (dbuf); register global prefetch; XOR-swizzled LDS.
// Swapped QK (A=K, B=Q): lane holds P[32 keys] for query (lane&31);
// PV A-frags built in-register via v_cvt_pk_bf16_f32 + v_permlane32_swap_b32.
// s_setprio(1) around MFMA clusters (T5).
// ---------------------------------------------------------------------------
__global__ __launch_bounds__(512, 4) void flash_kernel(
    const unsigned short* __restrict__ Q, const unsigned short* __restrict__ K,
    const unsigned short* __restrict__ Vt, unsigned short* __restrict__ O) {
  const int bh = blockIdx.x;        // 16
  const int m0 = blockIdx.y * 128;  // 32
  const int tid = threadIdx.x;
  const int lane = tid & 63, w = tid >> 6;
  const int ql = lane & 31, hi = lane >> 5;
  const int rt = w & 3;   // row tile (32 rows)
  const int kg = w >> 2;  // key group (2048 keys)
  const unsigned short* qp = Q + bh * (4096 * 64);
  const unsigned short* kp = K + bh * (4096 * 64);
  const unsigned short* vp = Vt + bh * (64 * 4096);

  __shared__ __align__(16) unsigned short SM[32768];  // 64 KB
  // Ks[buf]: SM + buf*8192 + kg*4096      [64 keys][64 d], swizzled
  // Vs[buf]: SM + 16384 + buf*8192 + kg*4096   [64 d][64 keys], swizzled
  unsigned short* Ksb = SM + kg * 4096;
  unsigned short* Vsb = SM + 16384 + kg * 4096;

  const int srow = (tid & 255) >> 3;  // 0..31 (and +32)
  const int c0s = tid & 7;            // source 16B chunk
  const int sw8 = (c0s ^ (srow & 7)) * 8;
  const unsigned short* kgp = kp + (kg * 2048 + srow) * 64 + c0s * 8;
  const unsigned short* vgp = vp + srow * 4096 + kg * 2048 + c0s * 8;

  // Q fragments (B operand of swapped QK, 32x32x16): lane: col=ql, k=hi*8+j.
  short8 qf[4];
  {
    const unsigned short* qrp = qp + (m0 + rt * 32 + ql) * 64 + hi * 8;
#pragma unroll
    for (int ks = 0; ks < 4; ++ks) qf[ks] = *(const short8*)(qrp + ks * 16);
  }

  floatx16 accO[2] = {};
  float accLp = 0.f;
  const int sx = ql & 7;

  // stage jt=0 into buf 0
  *(short8*)&Ksb[srow * 64 + sw8] = *(const short8*)(kgp);
  *(short8*)&Ksb[(srow + 32) * 64 + sw8] = *(const short8*)(kgp + 32 * 64);
  *(short8*)&Vsb[srow * 64 + sw8] = *(const short8*)(vgp);
  *(short8*)&Vsb[(srow + 32) * 64 + sw8] = *(const short8*)(vgp + 32 * 4096);
  __syncthreads();

  int buf = 0;
  for (int jt = 0; jt < 32; ++jt) {
    short8 kn0, kn1, vn0, vn1;
    if (jt < 31) {
      kn0 = *(const short8*)(kgp + (jt + 1) * 4096);
      kn1 = *(const short8*)(kgp + (jt + 1) * 4096 + 32 * 64);
      vn0 = *(const short8*)(vgp + (jt + 1) * 64);
      vn1 = *(const short8*)(vgp + (jt + 1) * 64 + 32 * 4096);
    }
    const unsigned short* Ks = Ksb + buf * 8192;
    const unsigned short* Vs = Vsb + buf * 8192;

    short8 pa[4];  // PV A-frags: keys 16*idx .. 16*idx+15
#pragma unroll
    for (int kt = 0; kt < 2; ++kt) {
      floatx16 c;
#pragma unroll
      for (int j = 0; j < 16; ++j) c[j] = 0.0f;
      __builtin_amdgcn_s_setprio(1);
#pragma unroll
      for (int ks = 0; ks < 4; ++ks) {
        const short8 kf = *(const short8*)&Ks[(kt * 32 + ql) * 64 +
                                             (((2 * ks + hi) ^ sx) * 8)];
        c = MFMA32(kf, qf[ks], c);
      }
      __builtin_amdgcn_s_setprio(0);
      // P = exp2(S); lane holds keys (r&3)+8*(r>>2)+4*hi (+32*kt), query ql.
      float e[16];
#pragma unroll
      for (int j = 0; j < 16; ++j) e[j] = EXP2(c[j]);
      accLp += (((e[0] + e[1]) + (e[2] + e[3])) +
                ((e[4] + e[5]) + (e[6] + e[7]))) +
               (((e[8] + e[9]) + (e[10] + e[11])) +
                ((e[12] + e[13]) + (e[14] + e[15])));
      // Build A-frags for PV (A row=query=ql, k=key hi*8+j per 16-key step):
      //   u[0]={a0_lo,b0_lo}  u[1]={c1_lo,d1_lo}
      //   u[2]={a0_hi,b0_hi}  u[3]={c1_hi,d1_hi}
      // swap(dst,src): new_dst={dst_lo,src_lo}, new_src={dst_hi,src_hi}.
#pragma unroll
      for (int s2 = 0; s2 < 2; ++s2) {
        unsigned int a0 = pkb(e[8 * s2 + 0], e[8 * s2 + 1]);
        unsigned int c1 = pkb(e[8 * s2 + 2], e[8 * s2 + 3]);
        unsigned int b0 = pkb(e[8 * s2 + 4], e[8 * s2 + 5]);
        unsigned int d1 = pkb(e[8 * s2 + 6], e[8 * s2 + 7]);
        asm("v_permlane32_swap_b32 %0, %1" : "+v"(a0), "+v"(b0));
        asm("v_permlane32_swap_b32 %0, %1" : "+v"(c1), "+v"(d1));
        union { unsigned int u[4]; short8 s; } cv;
        cv.u[0] = a0; cv.u[1] = c1; cv.u[2] = b0; cv.u[3] = d1;
        pa[kt * 2 + s2] = cv.s;
      }
    }
    // PV: D[q][d] += P[q][k] * V[k][d];  B-frag from Vs[d][k].
    __builtin_amdgcn_s_setprio(1);
#pragma unroll
    for (int dt = 0; dt < 2; ++dt)
#pragma unroll
      for (int ks2 = 0; ks2 < 4; ++ks2) {
        const short8 vf = *(const short8*)&Vs[(dt * 32 + ql) * 64 +
                                              (((2 * ks2 + hi) ^ sx) * 8)];
        accO[dt] = MFMA32(pa[ks2], vf, accO[dt]);
      }
    __builtin_amdgcn_s_setprio(0);
    // write next tile into buf^1 (its readers finished at jt-1's barrier)
    if (jt < 31) {
      unsigned short* Kw = Ksb + (buf ^ 1) * 8192;
      unsigned short* Vw = Vsb + (buf ^ 1) * 8192;
      *(short8*)&Kw[srow * 64 + sw8] = kn0;
      *(short8*)&Kw[(srow + 32) * 64 + sw8] = kn1;
      *(short8*)&Vw[srow * 64 + sw8] = vn0;
      *(short8*)&Vw[(srow + 32) * 64 + sw8] = vn1;
    }
    __syncthreads();
    buf ^= 1;
  }

  // kg reduction: kg=1 dumps accO (32 f32) + accLp; kg=0 adds.
  float* MB = (float*)SM;
  if (kg == 1) {
    float* dst = MB + (rt * 64 + lane) * 40;
#pragma unroll
    for (int dt = 0; dt < 2; ++dt)
#pragma unroll
      for (int r = 0; r < 16; ++r) dst[dt * 16 + r] = accO[dt][r];
    dst[32] = accLp;
  }
  __syncthreads();
  if (kg == 1) return;
  {
    const float* src = MB + (rt * 64 + lane) * 40;
#pragma unroll
    for (int dt = 0; dt < 2; ++dt)
#pragma unroll
      for (int r = 0; r < 16; ++r) accO[dt][r] += src[dt * 16 + r];
    accLp += src[32];
  }

  const float Lfull = accLp + __shfl(accLp, lane ^ 32, 64);
  const float invL = 1.0f / Lfull;
  const int b = bh >> 3, h = bh & 7;
#pragma unroll
  for (int r = 0; r < 16; ++r) {
    const int qrow = (r & 3) + 8 * (r >> 2) + 4 * hi;
    const float iv = __shfl(invL, qrow, 64);
    const int n = m0 + rt * 32 + qrow;
#pragma unroll
    for (int dt = 0; dt < 2; ++dt) {
      const int col = h * 64 + dt * 32 + ql;
      O[((b << 12) + n) * 512 + col] = f2b(accO[dt][r] * iv);
    }
  }
}

// ---------------------------------------------------------------------------
// Kernel 3: out projection — all-DMA dbuf single-barrier, 64x64, BK=64.
// ---------------------------------------------------------------------------
__global__ __launch_bounds__(256) void out_proj_kernel(
    const unsigned short* __restrict__ A, const unsigned short* __restrict__ wto,
    const float* __restrict__ bo, float* __restrict__ out) {
  const int m0 = blockIdx.x * 64, c0 = blockIdx.y * 64;
  __shared__ __align__(16) unsigned short As[2][64 * 64];  // 16 KB
  __shared__ __align__(16) unsigned short Bs[2][64 * 64];  // 16 KB
  const int tid = threadIdx.x;
  const int lane = tid & 63, w = tid >> 6;
  const int i = lane & 15, q = lane >> 4;
  const int wy = w >> 1, wx = w & 1;
  const int sl = i & 7;
  const int dr = lane >> 3, dc = lane & 7;
  const int sch = (dc ^ dr) * 8;
  const unsigned short* ag = A + (m0 + w * 16 + dr) * 512 + sch;
  const unsigned short* bg = wto + (c0 + w * 16 + dr) * 512 + sch;

  floatx4 acc[2][2] = {};
#pragma unroll
  for (int p = 0; p < 2; ++p) {
    dma16(ag + p * 8 * 512, &As[0][(w * 16 + p * 8) * 64]);
    dma16(bg + p * 8 * 512, &Bs[0][(w * 16 + p * 8) * 64]);
  }
  __syncthreads();

  int buf = 0;
  for (int ks = 0; ks < 8; ++ks) {
    if (ks < 7) {
      const int k1 = (ks + 1) * 64;
#pragma unroll
      for (int p = 0; p < 2; ++p) {
        dma16(ag + p * 8 * 512 + k1, &As[buf ^ 1][(w * 16 + p * 8) * 64]);
        dma16(bg + p * 8 * 512 + k1, &Bs[buf ^ 1][(w * 16 + p * 8) * 64]);
      }
    }
#pragma unroll
    for (int kc = 0; kc < 2; ++kc) {
      short8 af[2], bfr[2];
#pragma unroll
      for (int t = 0; t < 2; ++t)
        af[t] = *(const short8*)&As[buf][(wy * 32 + t * 16 + i) * 64 +
                                        (((kc * 4 + q) ^ sl) * 8)];
#pragma unroll
      for (int g = 0; g < 2; ++g)
        bfr[g] = *(const short8*)&Bs[buf][(wx * 32 + g * 16 + i) * 64 +
                                          (((kc * 4 + q) ^ sl) * 8)];
#pragma unroll
      for (int t = 0; t < 2; ++t)
#pragma unroll
        for (int g = 0; g < 2; ++g) acc[t][g] = MFMA16(af[t], bfr[g], acc[t][g]);
    }
    __syncthreads();
    buf ^= 1;
  }
#pragma unroll
  for (int t = 0; t < 2; ++t)
#pragma unroll
    for (int g = 0; g < 2; ++g) {
      const int col = c0 + wx * 32 + g * 16 + i;
      const float bias = bo[col];
#pragma unroll
      for (int r = 0; r < 4; ++r) {
        const int row = m0 + wy * 32 + t * 16 + q * 4 + r;
        out[row * 512 + col] = acc[t][g][r] + bias;
      }
    }
}

// ---------------------------------------------------------------------------
extern "C" void kernel_launch(void* const* d_in, const int* in_sizes, int n_in,
                              void* d_out, int out_size, void* d_ws,
                              size_t ws_size, hipStream_t stream) {
  const float* x = (const float*)d_in[0];
  const float* Wq = (const float*)d_in[1];
  const float* Wk = (const float*)d_in[2];
  const float* Wv = (const float*)d_in[3];
  const float* Wo = (const float*)d_in[4];
  const float* bo = (const float*)d_in[5];
  float* out = (float*)d_out;

  const size_t tsz = (size_t)16 * 4096 * 64;  // B*N*INNER elems
  unsigned short* qws = (unsigned short*)d_ws;
  unsigned short* kws = qws + tsz;
  unsigned short* vws = kws + tsz;
  unsigned short* ows = vws + tsz;
  unsigned short* wtq = ows + tsz;
  unsigned short* wtk = wtq + 512 * 512;
  unsigned short* wtv = wtk + 512 * 512;
  unsigned short* wto = wtv + 512 * 512;
  unsigned short* xb = wto + 512 * 512;  // x as bf16, [8192,512]

  prep_kernel<<<dim3(16, 16, 12), 256, 0, stream>>>(Wq, Wk, Wv, Wo, x, wtq,
                                                    wtk, wtv, wto, xb);
  qkv_fused_kernel<<<dim3(64, 16), 256, 0, stream>>>(xb, wtq, wtk, wtv, qws,
                                                     kws, vws);
  flash_kernel<<<dim3(16, 32), 512, 0, stream>>>(qws, kws, vws, ows);
  out_proj_kernel<<<dim3(128, 8), 256, 0, stream>>>(ows, wto, bo, out);
}